// Round 7
// baseline (403.876 us; speedup 1.0000x reference)
//
#include <hip/hip_runtime.h>
#include <math.h>

#define D 128

typedef __attribute__((ext_vector_type(8))) short bf16x8;
typedef __attribute__((ext_vector_type(4))) float f32x4;

__device__ __forceinline__ float sigmoidf_(float x) { return 1.f / (1.f + __expf(-x)); }
__device__ __forceinline__ float bf2f(unsigned short u) { return __uint_as_float(((unsigned)u) << 16); }
__device__ __forceinline__ unsigned short f2b(float f) {
  unsigned u = __float_as_uint(f);
  return (unsigned short)((u + 0x7fffu + ((u >> 16) & 1u)) >> 16);  // RNE
}

// ---------- fp32 -> bf16 convert ----------
__global__ void __launch_bounds__(256) k_f2b(const float* __restrict__ in,
                                             unsigned short* __restrict__ out, int n) {
  int i = blockIdx.x * 256 + threadIdx.x;
  if (i < n) out[i] = f2b(in[i]);
}

// ---------- pack W[h,k,d] -> MFMA B-fragment layout ----------
template <int NCOLS>
__global__ void __launch_bounds__(256) k_pack_w(const float* __restrict__ W,
                                                unsigned short* __restrict__ Bp) {
  int i = blockIdx.x * 256 + threadIdx.x;
  if (i >= 128 * NCOLS) return;
  int j = i & 7;
  int lane = (i >> 3) & 63;
  int rest = i >> 9;  // kb*(NCOLS/16)+db
  int db = rest % (NCOLS / 16);
  int kb = rest / (NCOLS / 16);
  int k = kb * 32 + ((lane >> 4) << 3) + j;
  int col = db * 16 + (lane & 15);
  int h = col >> 7, d = col & 127;
  Bp[i] = f2b(W[((size_t)h * 128 + k) * 128 + d]);
}

// ---------- pack GRU weight S[384][128] as B[k][col]=S[col][k] ----------
__global__ void __launch_bounds__(256) k_pack_gru(const float* __restrict__ S,
                                                  unsigned short* __restrict__ Bp) {
  int i = blockIdx.x * 256 + threadIdx.x;
  if (i >= 128 * 384) return;
  int j = i & 7;
  int lane = (i >> 3) & 63;
  int rest = i >> 9;  // kb*24+db
  int db = rest % 24;
  int kb = rest / 24;
  int k = kb * 32 + ((lane >> 4) << 3) + j;
  int col = db * 16 + (lane & 15);
  Bp[i] = f2b(S[(size_t)col * 128 + k]);
}

// ---------- MFMA GEMM: 32-row tiles; optional fused es/ed epilogue (NCOLS=512) ----------
template <int NCOLS, bool FUSE>
__global__ void __launch_bounds__(256) k_wh_mfma(const unsigned short* __restrict__ hb,
                                                 const unsigned short* __restrict__ Bp,
                                                 unsigned short* __restrict__ Whb,
                                                 const float* __restrict__ a_src,
                                                 const float* __restrict__ a_dst,
                                                 float* __restrict__ es,
                                                 float* __restrict__ ed) {
  const int n0 = blockIdx.x * 32;
  const int w = threadIdx.x >> 6;
  const int lane = threadIdx.x & 63;
  const int r = lane & 15, g = lane >> 4;
  constexpr int TPW = NCOLS / 64;
  f32x4 acc[2][TPW];
#pragma unroll
  for (int m = 0; m < 2; ++m)
#pragma unroll
    for (int t = 0; t < TPW; ++t) acc[m][t] = (f32x4)0.f;
  const int koff = g << 3;
#pragma unroll
  for (int kb = 0; kb < 4; ++kb) {
    bf16x8 a0 = *(const bf16x8*)&hb[(size_t)(n0 + r) * 128 + kb * 32 + koff];
    bf16x8 a1 = *(const bf16x8*)&hb[(size_t)(n0 + 16 + r) * 128 + kb * 32 + koff];
#pragma unroll
    for (int t = 0; t < TPW; ++t) {
      const int ct = w * TPW + t;
      bf16x8 b = *(const bf16x8*)&Bp[((size_t)(kb * (NCOLS / 16) + ct) * 64 + lane) * 8];
      acc[0][t] = __builtin_amdgcn_mfma_f32_16x16x32_bf16(a0, b, acc[0][t], 0, 0, 0);
      acc[1][t] = __builtin_amdgcn_mfma_f32_16x16x32_bf16(a1, b, acc[1][t], 0, 0, 0);
    }
  }
#pragma unroll
  for (int m = 0; m < 2; ++m) {
    const int rbase = n0 + m * 16 + g * 4;
#pragma unroll
    for (int t = 0; t < TPW; ++t) {
      const int col = (w * TPW + t) * 16 + r;
#pragma unroll
      for (int i = 0; i < 4; ++i) {
        Whb[(size_t)(rbase + i) * NCOLS + col] = f2b(acc[m][t][i]);
      }
    }
  }
  if constexpr (FUSE) {
    // head = w; d = t*16 + r
    float av[TPW], bv[TPW];
#pragma unroll
    for (int t = 0; t < TPW; ++t) {
      av[t] = a_src[w * 128 + t * 16 + r];
      bv[t] = a_dst[w * 128 + t * 16 + r];
    }
#pragma unroll
    for (int m = 0; m < 2; ++m) {
      float sp[4] = {}, dp[4] = {};
#pragma unroll
      for (int t = 0; t < TPW; ++t)
#pragma unroll
        for (int i = 0; i < 4; ++i) {
          sp[i] += acc[m][t][i] * av[t];
          dp[i] += acc[m][t][i] * bv[t];
        }
#pragma unroll
      for (int off = 1; off < 16; off <<= 1)
#pragma unroll
        for (int i = 0; i < 4; ++i) {
          sp[i] += __shfl_xor(sp[i], off);
          dp[i] += __shfl_xor(dp[i], off);
        }
      if (r == 0) {
        const int rbase = n0 + m * 16 + g * 4;
#pragma unroll
        for (int i = 0; i < 4; ++i) {
          es[(size_t)(rbase + i) * 4 + w] = sp[i];
          ed[(size_t)(rbase + i) * 4 + w] = dp[i];
        }
      }
    }
  }
}

// ---------- es/ed for H=1 (layer 4) ----------
__global__ void __launch_bounds__(256) k_es_ed1(const unsigned short* __restrict__ Whb,
                                                const float* __restrict__ a_src,
                                                const float* __restrict__ a_dst,
                                                float* __restrict__ es,
                                                float* __restrict__ ed, int N) {
  int w = blockIdx.x * 4 + (threadIdx.x >> 6);
  int lane = threadIdx.x & 63;
  if (w >= N) return;
  const unsigned short* row = Whb + (size_t)w * D;
  float x0 = bf2f(row[lane]), x1 = bf2f(row[lane + 64]);
  float s = x0 * a_src[lane] + x1 * a_src[lane + 64];
  float t = x0 * a_dst[lane] + x1 * a_dst[lane + 64];
#pragma unroll
  for (int off = 32; off; off >>= 1) {
    s += __shfl_down(s, off);
    t += __shfl_down(t, off);
  }
  if (lane == 0) {
    es[w] = s;
    ed[w] = t;
  }
}

// ---------- CSR build ----------
__global__ void __launch_bounds__(256) k_hist(const int* __restrict__ dst, int* __restrict__ deg, int E) {
  int e = blockIdx.x * 256 + threadIdx.x;
  if (e < E) atomicAdd(&deg[dst[e]], 1);
}

__global__ void __launch_bounds__(1024) k_scan(const int* __restrict__ deg, int* __restrict__ rowptr,
                                               int* __restrict__ fill, int N) {
  __shared__ int part[1024];
  const int tid = threadIdx.x;
  const int chunk = (N + 1023) / 1024;
  const int b = tid * chunk;
  const int e = min(N, b + chunk);
  int s = 0;
  for (int i = b; i < e; ++i) s += deg[i];
  part[tid] = s;
  __syncthreads();
  for (int off = 1; off < 1024; off <<= 1) {
    int v = (tid >= off) ? part[tid - off] : 0;
    __syncthreads();
    part[tid] += v;
    __syncthreads();
  }
  int run = (tid == 0) ? 0 : part[tid - 1];
  for (int i = b; i < e; ++i) {
    rowptr[i] = run;
    fill[i] = run;
    run += deg[i];
  }
  if (b < N && e == N) rowptr[N] = run;
}

__global__ void __launch_bounds__(256) k_scatter(const int* __restrict__ src, const int* __restrict__ dst,
                                                 int* __restrict__ fill, int* __restrict__ srcs, int E) {
  int e = blockIdx.x * 256 + threadIdx.x;
  if (e >= E) return;
  int pos = atomicAdd(&fill[dst[e]], 1);
  srcs[pos] = src[e];
}

// ---------- fused edge phase, H=4: 64 lanes per node, one bf16x8 per edge-lane ----------
// lane l: head = l>>4, dims [(l&15)*8, +8). 4 nodes per 256-thread block.
// EPI=0: write agg f32; EPI=1: write elu f32+bf16; EPI=2: write elu bf16 only
template <int EPI>
__global__ void __launch_bounds__(256) k_edge_fused4(const int* __restrict__ rowptr,
                                                     const int* __restrict__ srcs,
                                                     const float* __restrict__ es,
                                                     const float* __restrict__ ed,
                                                     const unsigned short* __restrict__ Whb,
                                                     float* __restrict__ outf,
                                                     unsigned short* __restrict__ outb,
                                                     int N) {
  const int t = blockIdx.x * 4 + (threadIdx.x >> 6);
  if (t >= N) return;
  const int lane = threadIdx.x & 63;
  const int q = lane & 15;
  const int b0 = rowptr[t];
  const int deg = rowptr[t + 1] - b0;
  if (deg == 0) {
    if (lane < 16) {
      if constexpr (EPI != 2) {
        *(float4*)&outf[(size_t)t * D + q * 8] = make_float4(0.f, 0.f, 0.f, 0.f);
        *(float4*)&outf[(size_t)t * D + q * 8 + 4] = make_float4(0.f, 0.f, 0.f, 0.f);
      }
      if constexpr (EPI != 0) {
        *(uint4*)&outb[(size_t)t * D + q * 8] = make_uint4(0u, 0u, 0u, 0u);
      }
    }
    return;
  }
  float edv[4];
#pragma unroll
  for (int h = 0; h < 4; ++h) edv[h] = ed[t * 4 + h];
  // ---- phase A: online softmax across 64 lanes; keep first-chunk state in regs ----
  float m[4], den[4], vreg[4];
  int sreg = 0;
#pragma unroll
  for (int h = 0; h < 4; ++h) {
    m[h] = -1e30f;
    den[h] = 0.f;
    vreg[h] = -1e30f;
  }
  for (int i = lane; i < deg; i += 64) {
    int s = srcs[b0 + i];
    float4 ev = *(const float4*)&es[(size_t)s * 4];
    float vv[4] = {ev.x + edv[0], ev.y + edv[1], ev.z + edv[2], ev.w + edv[3]};
#pragma unroll
    for (int h = 0; h < 4; ++h) {
      float v = vv[h];
      v = v > 0.f ? v : 0.2f * v;
      vv[h] = v;
      float nm = fmaxf(m[h], v);
      den[h] = den[h] * __expf(m[h] - nm) + __expf(v - nm);
      m[h] = nm;
    }
    if (i == lane) {
      sreg = s;
#pragma unroll
      for (int h = 0; h < 4; ++h) vreg[h] = vv[h];
    }
  }
#pragma unroll
  for (int off = 32; off; off >>= 1) {
#pragma unroll
    for (int h = 0; h < 4; ++h) {
      float om = __shfl_xor(m[h], off);
      float od = __shfl_xor(den[h], off);
      float nm = fmaxf(m[h], om);
      den[h] = den[h] * __expf(m[h] - nm) + od * __expf(om - nm);
      m[h] = nm;
    }
  }
  float rden[4];
#pragma unroll
  for (int h = 0; h < 4; ++h) rden[h] = 1.f / den[h];
  // ---- phase B: one 16B load per edge per lane ----
  float acc[8];
#pragma unroll
  for (int j = 0; j < 8; ++j) acc[j] = 0.f;
  const unsigned short* whl = Whb + lane * 8;  // lane's column slice of the 512-wide row
  for (int c0 = 0; c0 < deg; c0 += 64) {
    const int ce = min(64, deg - c0);
    float ar[4];
    int sr = 0;
#pragma unroll
    for (int h = 0; h < 4; ++h) ar[h] = 0.f;
    if (c0 == 0) {
      sr = sreg;
#pragma unroll
      for (int h = 0; h < 4; ++h) ar[h] = __expf(vreg[h] - m[h]) * rden[h];
    } else {
      int i = c0 + lane;
      if (i < deg) {
        int s = srcs[b0 + i];
        sr = s;
        float4 ev = *(const float4*)&es[(size_t)s * 4];
        float vv[4] = {ev.x + edv[0], ev.y + edv[1], ev.z + edv[2], ev.w + edv[3]};
#pragma unroll
        for (int h = 0; h < 4; ++h) {
          float v = vv[h];
          v = v > 0.f ? v : 0.2f * v;
          ar[h] = __expf(v - m[h]) * rden[h];
        }
      }
    }
#pragma unroll 2
    for (int e = 0; e < ce; ++e) {
      int s = __shfl(sr, e);
      float a0 = __shfl(ar[0], e);
      float a1 = __shfl(ar[1], e);
      float a2 = __shfl(ar[2], e);
      float a3 = __shfl(ar[3], e);
      float a = (lane < 32) ? ((lane < 16) ? a0 : a1) : ((lane < 48) ? a2 : a3);
      bf16x8 v = *(const bf16x8*)&whl[(size_t)s * 512];
#pragma unroll
      for (int j = 0; j < 8; ++j) {
        acc[j] += a * bf2f((unsigned short)v[j]);
      }
    }
  }
  // fold the 4 head-groups: lanes with same q end up with the full head-sum
#pragma unroll
  for (int j = 0; j < 8; ++j) {
    acc[j] += __shfl_xor(acc[j], 16);
    acc[j] += __shfl_xor(acc[j], 32);
  }
  if (lane < 16) {
    float o[8];
#pragma unroll
    for (int j = 0; j < 8; ++j) o[j] = acc[j] * 0.25f;
    if constexpr (EPI != 0) {
#pragma unroll
      for (int j = 0; j < 8; ++j) o[j] = o[j] > 0.f ? o[j] : expm1f(o[j]);
      uint4 pk;
      pk.x = (unsigned)f2b(o[0]) | ((unsigned)f2b(o[1]) << 16);
      pk.y = (unsigned)f2b(o[2]) | ((unsigned)f2b(o[3]) << 16);
      pk.z = (unsigned)f2b(o[4]) | ((unsigned)f2b(o[5]) << 16);
      pk.w = (unsigned)f2b(o[6]) | ((unsigned)f2b(o[7]) << 16);
      *(uint4*)&outb[(size_t)t * D + q * 8] = pk;
    }
    if constexpr (EPI != 2) {
      *(float4*)&outf[(size_t)t * D + q * 8] = make_float4(o[0], o[1], o[2], o[3]);
      *(float4*)&outf[(size_t)t * D + q * 8 + 4] = make_float4(o[4], o[5], o[6], o[7]);
    }
  }
}

// ---------- fused edge phase, H=1: 16-lane group per node (row = 256 B) ----------
template <int EPI>
__global__ void __launch_bounds__(256) k_edge_fused1(const int* __restrict__ rowptr,
                                                     const int* __restrict__ srcs,
                                                     const float* __restrict__ es,
                                                     const float* __restrict__ ed,
                                                     const unsigned short* __restrict__ Whb,
                                                     float* __restrict__ outf,
                                                     unsigned short* __restrict__ outb,
                                                     int N) {
  const int t = blockIdx.x * 16 + (threadIdx.x >> 4);
  if (t >= N) return;
  const int lane = threadIdx.x & 63;
  const int q = lane & 15;
  const int gbase = lane & 48;
  const int b0 = rowptr[t];
  const int deg = rowptr[t + 1] - b0;
  if (deg == 0) {
    if constexpr (EPI != 2) {
      *(float4*)&outf[(size_t)t * D + q * 8] = make_float4(0.f, 0.f, 0.f, 0.f);
      *(float4*)&outf[(size_t)t * D + q * 8 + 4] = make_float4(0.f, 0.f, 0.f, 0.f);
    }
    if constexpr (EPI != 0) {
      *(uint4*)&outb[(size_t)t * D + q * 8] = make_uint4(0u, 0u, 0u, 0u);
    }
    return;
  }
  float edv = ed[t];
  float m = -1e30f, den = 0.f, vreg = -1e30f;
  int sreg = 0;
  for (int i = q; i < deg; i += 16) {
    int s = srcs[b0 + i];
    float v = es[s] + edv;
    v = v > 0.f ? v : 0.2f * v;
    float nm = fmaxf(m, v);
    den = den * __expf(m - nm) + __expf(v - nm);
    m = nm;
    if (i == q) {
      sreg = s;
      vreg = v;
    }
  }
#pragma unroll
  for (int off = 1; off < 16; off <<= 1) {
    float om = __shfl_xor(m, off);
    float od = __shfl_xor(den, off);
    float nm = fmaxf(m, om);
    den = den * __expf(m - nm) + od * __expf(om - nm);
    m = nm;
  }
  float rden = 1.f / den;
  float acc[8];
#pragma unroll
  for (int j = 0; j < 8; ++j) acc[j] = 0.f;
  const unsigned short* whq = Whb + q * 8;
  for (int c0 = 0; c0 < deg; c0 += 16) {
    const int ce = min(16, deg - c0);
    float ar = 0.f;
    int sr = 0;
    if (c0 == 0) {
      sr = sreg;
      ar = __expf(vreg - m) * rden;
    } else {
      int i = c0 + q;
      if (i < deg) {
        int s = srcs[b0 + i];
        sr = s;
        float v = es[s] + edv;
        v = v > 0.f ? v : 0.2f * v;
        ar = __expf(v - m) * rden;
      }
    }
#pragma unroll 2
    for (int e = 0; e < ce; ++e) {
      int s = __shfl(sr, gbase + e);
      float a = __shfl(ar, gbase + e);
      bf16x8 v = *(const bf16x8*)&whq[(size_t)s * D];
#pragma unroll
      for (int j = 0; j < 8; ++j) {
        acc[j] += a * bf2f((unsigned short)v[j]);
      }
    }
  }
  float o[8];
#pragma unroll
  for (int j = 0; j < 8; ++j) o[j] = acc[j];
  if constexpr (EPI != 0) {
#pragma unroll
    for (int j = 0; j < 8; ++j) o[j] = o[j] > 0.f ? o[j] : expm1f(o[j]);
    uint4 pk;
    pk.x = (unsigned)f2b(o[0]) | ((unsigned)f2b(o[1]) << 16);
    pk.y = (unsigned)f2b(o[2]) | ((unsigned)f2b(o[3]) << 16);
    pk.z = (unsigned)f2b(o[4]) | ((unsigned)f2b(o[5]) << 16);
    pk.w = (unsigned)f2b(o[6]) | ((unsigned)f2b(o[7]) << 16);
    *(uint4*)&outb[(size_t)t * D + q * 8] = pk;
  }
  if constexpr (EPI != 2) {
    *(float4*)&outf[(size_t)t * D + q * 8] = make_float4(o[0], o[1], o[2], o[3]);
    *(float4*)&outf[(size_t)t * D + q * 8 + 4] = make_float4(o[4], o[5], o[6], o[7]);
  }
}

// ---------- fused GRU (32-row tiles): gi=xb@Wih^T; gh=hb@Whh^T; gates ----------
__global__ void __launch_bounds__(256) k_gru_mfma(const unsigned short* __restrict__ xb,
                                                  const unsigned short* __restrict__ hb,
                                                  const float* __restrict__ hf,
                                                  const unsigned short* __restrict__ Bih,
                                                  const unsigned short* __restrict__ Bhh,
                                                  const float* __restrict__ bih,
                                                  const float* __restrict__ bhh,
                                                  float* __restrict__ houtf,
                                                  unsigned short* __restrict__ houtb) {
  const int n0 = blockIdx.x * 32;
  const int w = threadIdx.x >> 6;
  const int lane = threadIdx.x & 63;
  const int r = lane & 15, g = lane >> 4;
  f32x4 ai[3][2][2], ah[3][2][2];  // [gate][t][rowtile]
#pragma unroll
  for (int p = 0; p < 3; ++p)
#pragma unroll
    for (int t = 0; t < 2; ++t)
#pragma unroll
      for (int m = 0; m < 2; ++m) {
        ai[p][t][m] = (f32x4)0.f;
        ah[p][t][m] = (f32x4)0.f;
      }
  const int koff = g << 3;
#pragma unroll
  for (int kb = 0; kb < 4; ++kb) {
    bf16x8 ax[2], ahr[2];
#pragma unroll
    for (int m = 0; m < 2; ++m) {
      const size_t abase = (size_t)(n0 + m * 16 + r) * 128 + kb * 32 + koff;
      ax[m] = *(const bf16x8*)&xb[abase];
      ahr[m] = *(const bf16x8*)&hb[abase];
    }
#pragma unroll
    for (int p = 0; p < 3; ++p) {
#pragma unroll
      for (int t = 0; t < 2; ++t) {
        const int ct = p * 8 + w * 2 + t;
        bf16x8 bi = *(const bf16x8*)&Bih[((size_t)(kb * 24 + ct) * 64 + lane) * 8];
        bf16x8 bh = *(const bf16x8*)&Bhh[((size_t)(kb * 24 + ct) * 64 + lane) * 8];
#pragma unroll
        for (int m = 0; m < 2; ++m) {
          ai[p][t][m] = __builtin_amdgcn_mfma_f32_16x16x32_bf16(ax[m], bi, ai[p][t][m], 0, 0, 0);
          ah[p][t][m] = __builtin_amdgcn_mfma_f32_16x16x32_bf16(ahr[m], bh, ah[p][t][m], 0, 0, 0);
        }
      }
    }
  }
#pragma unroll
  for (int m = 0; m < 2; ++m) {
#pragma unroll
    for (int t = 0; t < 2; ++t) {
      const int j = (w * 2 + t) * 16 + r;
      const float bir = bih[j], biz = bih[128 + j], bin = bih[256 + j];
      const float bhr = bhh[j], bhz = bhh[128 + j], bhn = bhh[256 + j];
#pragma unroll
      for (int i = 0; i < 4; ++i) {
        const int row = n0 + m * 16 + g * 4 + i;
        float rr = sigmoidf_(ai[0][t][m][i] + bir + ah[0][t][m][i] + bhr);
        float z = sigmoidf_(ai[1][t][m][i] + biz + ah[1][t][m][i] + bhz);
        float nn = tanhf(ai[2][t][m][i] + bin + rr * (ah[2][t][m][i] + bhn));
        float hp = hf[(size_t)row * 128 + j];
        float o = (1.f - z) * nn + z * hp;
        houtf[(size_t)row * 128 + j] = o;
        houtb[(size_t)row * 128 + j] = f2b(o);
      }
    }
  }
}

// ---------- final: out[n] = sigmoid(dot(h[n,:], W5) + b5) ----------
__global__ void __launch_bounds__(256) k_final(const float* __restrict__ h, const float* __restrict__ W5,
                                               const float* __restrict__ b5, float* __restrict__ out, int N) {
  int w = blockIdx.x * 4 + (threadIdx.x >> 6);
  int lane = threadIdx.x & 63;
  if (w >= N) return;
  float x = h[(size_t)w * D + lane] * W5[lane] + h[(size_t)w * D + lane + 64] * W5[lane + 64];
#pragma unroll
  for (int off = 32; off; off >>= 1) x += __shfl_down(x, off);
  if (lane == 0) out[w] = sigmoidf_(x + b5[0]);
}

extern "C" void kernel_launch(void* const* d_in, const int* in_sizes, int n_in,
                              void* d_out, int out_size, void* d_ws, size_t ws_size,
                              hipStream_t stream) {
  const float* h0 = (const float*)d_in[0];
  const int* ei = (const int*)d_in[1];
  const float* W1 = (const float*)d_in[2];
  const float* as1 = (const float*)d_in[3];
  const float* ad1 = (const float*)d_in[4];
  const float* W2 = (const float*)d_in[5];
  const float* as2 = (const float*)d_in[6];
  const float* ad2 = (const float*)d_in[7];
  const float* W3 = (const float*)d_in[8];
  const float* as3 = (const float*)d_in[9];
  const float* ad3 = (const float*)d_in[10];
  const float* W4 = (const float*)d_in[11];
  const float* as4 = (const float*)d_in[12];
  const float* ad4 = (const float*)d_in[13];
  const float* Wih = (const float*)d_in[14];
  const float* Whh = (const float*)d_in[15];
  const float* bih = (const float*)d_in[16];
  const float* bhh = (const float*)d_in[17];
  const float* W5 = (const float*)d_in[18];
  const float* b5 = (const float*)d_in[19];

  const int N = in_sizes[0] / D;  // 20000
  const int E = in_sizes[1] / 2;  // 320000
  const int* src = ei;
  const int* dst = ei + E;

  // ---- workspace layout ----
  float* ws = (float*)d_ws;
  unsigned short* Whb = (unsigned short*)ws;          // N*512 us
  float* hA = ws + (size_t)N * 256;                   // N*128 f32
  float* hB = hA + (size_t)N * 128;                   // N*128 f32
  unsigned short* xb = (unsigned short*)(hB + (size_t)N * 128);  // N*128 us
  float* es = (float*)(xb + (size_t)N * 128);         // N*4
  float* ed = es + (size_t)N * 4;                     // N*4
  unsigned short* h0b = (unsigned short*)(ed + (size_t)N * 4);   // N*128 us
  unsigned short* hAb = h0b + (size_t)N * 128;        // N*128 us
  unsigned short* hBb = hAb + (size_t)N * 128;        // N*128 us
  unsigned short* BpW = hBb + (size_t)N * 128;        // 128*512 us
  unsigned short* Bih = BpW + 128 * 512;              // 128*384 us
  unsigned short* Bhh = Bih + 128 * 384;              // 128*384 us
  int* deg = (int*)(Bhh + 128 * 384);                 // N
  int* rowptr = deg + N;                              // N+1
  int* fill = rowptr + N + 1;                         // N
  int* srcs = fill + N;                               // E

  // ---- one-time prep ----
  k_f2b<<<(N * 128 + 255) / 256, 256, 0, stream>>>(h0, h0b, N * 128);
  k_pack_gru<<<(128 * 384 + 255) / 256, 256, 0, stream>>>(Wih, Bih);
  k_pack_gru<<<(128 * 384 + 255) / 256, 256, 0, stream>>>(Whh, Bhh);
  hipMemsetAsync(deg, 0, (size_t)N * 4, stream);
  k_hist<<<(E + 255) / 256, 256, 0, stream>>>(dst, deg, E);
  k_scan<<<1, 1024, 0, stream>>>(deg, rowptr, fill, N);
  k_scatter<<<(E + 255) / 256, 256, 0, stream>>>(src, dst, fill, srcs, E);

  const int gW = N / 32;         // 625
  const int gE4 = (N + 3) / 4;   // 5000
  const int gE1 = (N + 15) / 16; // 1250
  // ---- layer 1: H=4, no GRU; edge emits elu as f32 (hA) + bf16 (hAb) ----
  k_pack_w<512><<<(128 * 512 + 255) / 256, 256, 0, stream>>>(W1, BpW);
  k_wh_mfma<512, true><<<gW, 256, 0, stream>>>(h0b, BpW, Whb, as1, ad1, es, ed);
  k_edge_fused4<1><<<gE4, 256, 0, stream>>>(rowptr, srcs, es, ed, Whb, hA, hAb, N);
  // ---- layer 2: H=4, GRU; edge emits xb bf16 only ----
  k_pack_w<512><<<(128 * 512 + 255) / 256, 256, 0, stream>>>(W2, BpW);
  k_wh_mfma<512, true><<<gW, 256, 0, stream>>>(hAb, BpW, Whb, as2, ad2, es, ed);
  k_edge_fused4<2><<<gE4, 256, 0, stream>>>(rowptr, srcs, es, ed, Whb, nullptr, xb, N);
  k_gru_mfma<<<gW, 256, 0, stream>>>(xb, hAb, hA, Bih, Bhh, bih, bhh, hB, hBb);
  // ---- layer 3: H=4, GRU ----
  k_pack_w<512><<<(128 * 512 + 255) / 256, 256, 0, stream>>>(W3, BpW);
  k_wh_mfma<512, true><<<gW, 256, 0, stream>>>(hBb, BpW, Whb, as3, ad3, es, ed);
  k_edge_fused4<2><<<gE4, 256, 0, stream>>>(rowptr, srcs, es, ed, Whb, nullptr, xb, N);
  k_gru_mfma<<<gW, 256, 0, stream>>>(xb, hBb, hB, Bih, Bhh, bih, bhh, hA, hAb);
  // ---- layer 4: H=1, GRU ----
  k_pack_w<128><<<(128 * 128 + 255) / 256, 256, 0, stream>>>(W4, BpW);
  k_wh_mfma<128, false><<<gW, 256, 0, stream>>>(hAb, BpW, Whb, nullptr, nullptr, nullptr, nullptr);
  k_es_ed1<<<(N + 3) / 4, 256, 0, stream>>>(Whb, as4, ad4, es, ed, N);
  k_edge_fused1<2><<<gE1, 256, 0, stream>>>(rowptr, srcs, es, ed, Whb, nullptr, xb, N);
  k_gru_mfma<<<gW, 256, 0, stream>>>(xb, hAb, hA, Bih, Bhh, bih, bhh, hB, hBb);

  // ---- output head ----
  k_final<<<(N + 3) / 4, 256, 0, stream>>>(hB, W5, b5, (float*)d_out, N);
}

// Round 8
// 362.269 us; speedup vs baseline: 1.1149x; 1.1149x over previous
//
#include <hip/hip_runtime.h>
#include <math.h>

#define D 128

typedef __attribute__((ext_vector_type(8))) short bf16x8;
typedef __attribute__((ext_vector_type(4))) float f32x4;

__device__ __forceinline__ float sigmoidf_(float x) { return 1.f / (1.f + __expf(-x)); }
__device__ __forceinline__ float bf2f(unsigned short u) { return __uint_as_float(((unsigned)u) << 16); }
__device__ __forceinline__ float u2f_lo(unsigned u) { return __uint_as_float(u << 16); }
__device__ __forceinline__ float u2f_hi(unsigned u) { return __uint_as_float(u & 0xffff0000u); }
__device__ __forceinline__ unsigned short f2b(float f) {
  unsigned u = __float_as_uint(f);
  return (unsigned short)((u + 0x7fffu + ((u >> 16) & 1u)) >> 16);  // RNE
}

// ---------- fp32 -> bf16 convert ----------
__global__ void __launch_bounds__(256) k_f2b(const float* __restrict__ in,
                                             unsigned short* __restrict__ out, int n) {
  int i = blockIdx.x * 256 + threadIdx.x;
  if (i < n) out[i] = f2b(in[i]);
}

// ---------- packing helpers ----------
__device__ __forceinline__ void pack_w_elem(const float* __restrict__ W,
                                            unsigned short* __restrict__ Bp, int i, int ncols16) {
  int j = i & 7;
  int lane = (i >> 3) & 63;
  int rest = i >> 9;
  int db = rest % ncols16;
  int kb = rest / ncols16;
  int k = kb * 32 + ((lane >> 4) << 3) + j;
  int col = db * 16 + (lane & 15);
  int h = col >> 7, d = col & 127;
  Bp[i] = f2b(W[((size_t)h * 128 + k) * 128 + d]);
}
__device__ __forceinline__ void pack_gru_elem(const float* __restrict__ S,
                                              unsigned short* __restrict__ Bp, int i) {
  int j = i & 7;
  int lane = (i >> 3) & 63;
  int rest = i >> 9;
  int db = rest % 24;
  int kb = rest / 24;
  int k = kb * 32 + ((lane >> 4) << 3) + j;
  int col = db * 16 + (lane & 15);
  Bp[i] = f2b(S[(size_t)col * 128 + k]);
}

// ---------- pack ALL weights in one dispatch ----------
// segments: B1,B2,B3 = 65536 each; B4 = 16384; Bih,Bhh = 49152 each. total 311296
__global__ void __launch_bounds__(256) k_pack_all(const float* __restrict__ W1, const float* __restrict__ W2,
                                                  const float* __restrict__ W3, const float* __restrict__ W4,
                                                  const float* __restrict__ Wih, const float* __restrict__ Whh,
                                                  unsigned short* __restrict__ B1, unsigned short* __restrict__ B2,
                                                  unsigned short* __restrict__ B3, unsigned short* __restrict__ B4,
                                                  unsigned short* __restrict__ Bih, unsigned short* __restrict__ Bhh) {
  int i = blockIdx.x * 256 + threadIdx.x;
  if (i < 65536) pack_w_elem(W1, B1, i, 32);
  else if (i < 131072) pack_w_elem(W2, B2, i - 65536, 32);
  else if (i < 196608) pack_w_elem(W3, B3, i - 131072, 32);
  else if (i < 212992) pack_w_elem(W4, B4, i - 196608, 8);
  else if (i < 262144) pack_gru_elem(Wih, Bih, i - 212992);
  else if (i < 311296) pack_gru_elem(Whh, Bhh, i - 262144);
}

// ---------- MFMA GEMM: 16-row tiles; optional fused es/ed epilogue (NCOLS=512) ----------
template <int NCOLS, bool FUSE>
__global__ void __launch_bounds__(256) k_wh_mfma(const unsigned short* __restrict__ hb,
                                                 const unsigned short* __restrict__ Bp,
                                                 unsigned short* __restrict__ Whb,
                                                 const float* __restrict__ a_src,
                                                 const float* __restrict__ a_dst,
                                                 float* __restrict__ es,
                                                 float* __restrict__ ed) {
  const int n0 = blockIdx.x * 16;
  const int w = threadIdx.x >> 6;
  const int lane = threadIdx.x & 63;
  const int r = lane & 15, g = lane >> 4;
  constexpr int TPW = NCOLS / 64;
  f32x4 acc[TPW];
#pragma unroll
  for (int t = 0; t < TPW; ++t) acc[t] = (f32x4)0.f;
  const int koff = g << 3;
#pragma unroll
  for (int kb = 0; kb < 4; ++kb) {
    bf16x8 a = *(const bf16x8*)&hb[(size_t)(n0 + r) * 128 + kb * 32 + koff];
#pragma unroll
    for (int t = 0; t < TPW; ++t) {
      const int ct = w * TPW + t;
      bf16x8 b = *(const bf16x8*)&Bp[((size_t)(kb * (NCOLS / 16) + ct) * 64 + lane) * 8];
      acc[t] = __builtin_amdgcn_mfma_f32_16x16x32_bf16(a, b, acc[t], 0, 0, 0);
    }
  }
  const int rbase = n0 + g * 4;
#pragma unroll
  for (int t = 0; t < TPW; ++t) {
    const int col = (w * TPW + t) * 16 + r;
#pragma unroll
    for (int i = 0; i < 4; ++i) {
      Whb[(size_t)(rbase + i) * NCOLS + col] = f2b(acc[t][i]);
    }
  }
  if constexpr (FUSE) {
    // head = w (TPW==8); d = t*16 + r
    float av[TPW], bv[TPW];
#pragma unroll
    for (int t = 0; t < TPW; ++t) {
      av[t] = a_src[w * 128 + t * 16 + r];
      bv[t] = a_dst[w * 128 + t * 16 + r];
    }
    float sp[4] = {}, dp[4] = {};
#pragma unroll
    for (int t = 0; t < TPW; ++t)
#pragma unroll
      for (int i = 0; i < 4; ++i) {
        sp[i] += acc[t][i] * av[t];
        dp[i] += acc[t][i] * bv[t];
      }
#pragma unroll
    for (int off = 1; off < 16; off <<= 1)
#pragma unroll
      for (int i = 0; i < 4; ++i) {
        sp[i] += __shfl_xor(sp[i], off);
        dp[i] += __shfl_xor(dp[i], off);
      }
    if (r == 0) {
#pragma unroll
      for (int i = 0; i < 4; ++i) {
        es[(size_t)(rbase + i) * 4 + w] = sp[i];
        ed[(size_t)(rbase + i) * 4 + w] = dp[i];
      }
    }
  }
}

// ---------- es/ed for H=1 (layer 4) ----------
__global__ void __launch_bounds__(256) k_es_ed1(const unsigned short* __restrict__ Whb,
                                                const float* __restrict__ a_src,
                                                const float* __restrict__ a_dst,
                                                float* __restrict__ es,
                                                float* __restrict__ ed, int N) {
  int w = blockIdx.x * 4 + (threadIdx.x >> 6);
  int lane = threadIdx.x & 63;
  if (w >= N) return;
  const unsigned short* row = Whb + (size_t)w * D;
  float x0 = bf2f(row[lane]), x1 = bf2f(row[lane + 64]);
  float s = x0 * a_src[lane] + x1 * a_src[lane + 64];
  float t = x0 * a_dst[lane] + x1 * a_dst[lane + 64];
#pragma unroll
  for (int off = 32; off; off >>= 1) {
    s += __shfl_down(s, off);
    t += __shfl_down(t, off);
  }
  if (lane == 0) {
    es[w] = s;
    ed[w] = t;
  }
}

// ---------- CSR build ----------
__global__ void __launch_bounds__(256) k_hist(const int* __restrict__ dst, int* __restrict__ deg, int E) {
  int e = blockIdx.x * 256 + threadIdx.x;
  if (e < E) atomicAdd(&deg[dst[e]], 1);
}

__global__ void __launch_bounds__(1024) k_scan(const int* __restrict__ deg, int* __restrict__ rowptr,
                                               int* __restrict__ fill, int N) {
  __shared__ int part[1024];
  const int tid = threadIdx.x;
  const int chunk = (N + 1023) / 1024;
  const int b = tid * chunk;
  const int e = min(N, b + chunk);
  int s = 0;
  for (int i = b; i < e; ++i) s += deg[i];
  part[tid] = s;
  __syncthreads();
  for (int off = 1; off < 1024; off <<= 1) {
    int v = (tid >= off) ? part[tid - off] : 0;
    __syncthreads();
    part[tid] += v;
    __syncthreads();
  }
  int run = (tid == 0) ? 0 : part[tid - 1];
  for (int i = b; i < e; ++i) {
    rowptr[i] = run;
    fill[i] = run;
    run += deg[i];
  }
  if (b < N && e == N) rowptr[N] = run;
}

__global__ void __launch_bounds__(256) k_scatter(const int* __restrict__ src, const int* __restrict__ dst,
                                                 int* __restrict__ fill, int* __restrict__ srcs, int E) {
  int e = blockIdx.x * 256 + threadIdx.x;
  if (e >= E) return;
  int pos = atomicAdd(&fill[dst[e]], 1);
  srcs[pos] = src[e];
}

// ---------- fused edge phase v4 (H=4): 64 lanes/node, LDS-staged alpha/offset ----------
// EPI=0: agg f32; EPI=1: elu f32 + bf16; EPI=2: elu bf16 only
template <int EPI>
__global__ void __launch_bounds__(256) k_edge_fused4(const int* __restrict__ rowptr,
                                                     const int* __restrict__ srcs,
                                                     const float* __restrict__ es,
                                                     const float* __restrict__ ed,
                                                     const unsigned short* __restrict__ Whb,
                                                     float* __restrict__ outf,
                                                     unsigned short* __restrict__ outb,
                                                     int N) {
  __shared__ unsigned s_off[4][64];
  __shared__ float s_af[4][64][4];
  const int wid = threadIdx.x >> 6;
  const int t = blockIdx.x * 4 + wid;
  if (t >= N) return;
  const int lane = threadIdx.x & 63;
  const int q = lane & 15;
  const int b0 = rowptr[t];
  const int deg = rowptr[t + 1] - b0;
  if (deg == 0) {
    if (lane < 16) {
      if constexpr (EPI != 2) {
        *(float4*)&outf[(size_t)t * D + q * 8] = make_float4(0.f, 0.f, 0.f, 0.f);
        *(float4*)&outf[(size_t)t * D + q * 8 + 4] = make_float4(0.f, 0.f, 0.f, 0.f);
      }
      if constexpr (EPI != 0) {
        *(uint4*)&outb[(size_t)t * D + q * 8] = make_uint4(0u, 0u, 0u, 0u);
      }
    }
    return;
  }
  float edv[4];
#pragma unroll
  for (int h = 0; h < 4; ++h) edv[h] = ed[t * 4 + h];
  // ---- phase A: online softmax across 64 lanes; keep first-chunk state in regs ----
  float m[4], den[4], vreg[4];
  int sreg = 0;
#pragma unroll
  for (int h = 0; h < 4; ++h) {
    m[h] = -1e30f;
    den[h] = 0.f;
    vreg[h] = -1e30f;
  }
  for (int i = lane; i < deg; i += 64) {
    int s = srcs[b0 + i];
    float4 ev = *(const float4*)&es[(size_t)s * 4];
    float vv[4] = {ev.x + edv[0], ev.y + edv[1], ev.z + edv[2], ev.w + edv[3]};
#pragma unroll
    for (int h = 0; h < 4; ++h) {
      float v = vv[h];
      v = v > 0.f ? v : 0.2f * v;
      vv[h] = v;
      float nm = fmaxf(m[h], v);
      den[h] = den[h] * __expf(m[h] - nm) + __expf(v - nm);
      m[h] = nm;
    }
    if (i == lane) {
      sreg = s;
#pragma unroll
      for (int h = 0; h < 4; ++h) vreg[h] = vv[h];
    }
  }
#pragma unroll
  for (int off = 32; off; off >>= 1) {
#pragma unroll
    for (int h = 0; h < 4; ++h) {
      float om = __shfl_xor(m[h], off);
      float od = __shfl_xor(den[h], off);
      float nm = fmaxf(m[h], om);
      den[h] = den[h] * __expf(m[h] - nm) + od * __expf(om - nm);
      m[h] = nm;
    }
  }
  float rden[4];
#pragma unroll
  for (int h = 0; h < 4; ++h) rden[h] = 1.f / den[h];
  // ---- phase B: LDS-staged {offset, alpha}; 1 dwordx4 per edge per lane ----
  float acc[8];
#pragma unroll
  for (int j = 0; j < 8; ++j) acc[j] = 0.f;
  const char* wbase = (const char*)Whb;
  const unsigned laneByte = (unsigned)lane * 16u;
  const int h4 = lane >> 4;
  for (int c0 = 0; c0 < deg; c0 += 64) {
    const int ce = min(64, deg - c0);
    if (c0 == 0) {
      if (lane < deg) {
        s_off[wid][lane] = (unsigned)sreg << 10;  // *1024 bytes per row
#pragma unroll
        for (int h = 0; h < 4; ++h)
          s_af[wid][lane][h] = __expf(vreg[h] - m[h]) * rden[h];
      }
    } else {
      int i = c0 + lane;
      if (i < deg) {
        int s = srcs[b0 + i];
        s_off[wid][lane] = (unsigned)s << 10;
        float4 ev = *(const float4*)&es[(size_t)s * 4];
        float vv[4] = {ev.x + edv[0], ev.y + edv[1], ev.z + edv[2], ev.w + edv[3]};
#pragma unroll
        for (int h = 0; h < 4; ++h) {
          float v = vv[h];
          v = v > 0.f ? v : 0.2f * v;
          s_af[wid][lane][h] = __expf(v - m[h]) * rden[h];
        }
      }
    }
#pragma unroll 4
    for (int e = 0; e < ce; ++e) {
      unsigned idx = s_off[wid][e] + laneByte;
      float af = s_af[wid][e][h4];
      uint4 v = *(const uint4*)(wbase + idx);
      acc[0] += af * u2f_lo(v.x);
      acc[1] += af * u2f_hi(v.x);
      acc[2] += af * u2f_lo(v.y);
      acc[3] += af * u2f_hi(v.y);
      acc[4] += af * u2f_lo(v.z);
      acc[5] += af * u2f_hi(v.z);
      acc[6] += af * u2f_lo(v.w);
      acc[7] += af * u2f_hi(v.w);
    }
  }
  // fold 4 head-groups -> head-mean
#pragma unroll
  for (int j = 0; j < 8; ++j) {
    acc[j] += __shfl_xor(acc[j], 16);
    acc[j] += __shfl_xor(acc[j], 32);
  }
  if (lane < 16) {
    float o[8];
#pragma unroll
    for (int j = 0; j < 8; ++j) o[j] = acc[j] * 0.25f;
    if constexpr (EPI != 0) {
#pragma unroll
      for (int j = 0; j < 8; ++j) o[j] = o[j] > 0.f ? o[j] : expm1f(o[j]);
      uint4 pk;
      pk.x = (unsigned)f2b(o[0]) | ((unsigned)f2b(o[1]) << 16);
      pk.y = (unsigned)f2b(o[2]) | ((unsigned)f2b(o[3]) << 16);
      pk.z = (unsigned)f2b(o[4]) | ((unsigned)f2b(o[5]) << 16);
      pk.w = (unsigned)f2b(o[6]) | ((unsigned)f2b(o[7]) << 16);
      *(uint4*)&outb[(size_t)t * D + q * 8] = pk;
    }
    if constexpr (EPI != 2) {
      *(float4*)&outf[(size_t)t * D + q * 8] = make_float4(o[0], o[1], o[2], o[3]);
      *(float4*)&outf[(size_t)t * D + q * 8 + 4] = make_float4(o[4], o[5], o[6], o[7]);
    }
  }
}

// ---------- fused edge phase, H=1: 16-lane group per node (row = 256 B) ----------
template <int EPI>
__global__ void __launch_bounds__(256) k_edge_fused1(const int* __restrict__ rowptr,
                                                     const int* __restrict__ srcs,
                                                     const float* __restrict__ es,
                                                     const float* __restrict__ ed,
                                                     const unsigned short* __restrict__ Whb,
                                                     float* __restrict__ outf,
                                                     unsigned short* __restrict__ outb,
                                                     int N) {
  const int t = blockIdx.x * 16 + (threadIdx.x >> 4);
  if (t >= N) return;
  const int lane = threadIdx.x & 63;
  const int q = lane & 15;
  const int gbase = lane & 48;
  const int b0 = rowptr[t];
  const int deg = rowptr[t + 1] - b0;
  if (deg == 0) {
    if constexpr (EPI != 2) {
      *(float4*)&outf[(size_t)t * D + q * 8] = make_float4(0.f, 0.f, 0.f, 0.f);
      *(float4*)&outf[(size_t)t * D + q * 8 + 4] = make_float4(0.f, 0.f, 0.f, 0.f);
    }
    if constexpr (EPI != 0) {
      *(uint4*)&outb[(size_t)t * D + q * 8] = make_uint4(0u, 0u, 0u, 0u);
    }
    return;
  }
  float edv = ed[t];
  float m = -1e30f, den = 0.f, vreg = -1e30f;
  int sreg = 0;
  for (int i = q; i < deg; i += 16) {
    int s = srcs[b0 + i];
    float v = es[s] + edv;
    v = v > 0.f ? v : 0.2f * v;
    float nm = fmaxf(m, v);
    den = den * __expf(m - nm) + __expf(v - nm);
    m = nm;
    if (i == q) {
      sreg = s;
      vreg = v;
    }
  }
#pragma unroll
  for (int off = 1; off < 16; off <<= 1) {
    float om = __shfl_xor(m, off);
    float od = __shfl_xor(den, off);
    float nm = fmaxf(m, om);
    den = den * __expf(m - nm) + od * __expf(om - nm);
    m = nm;
  }
  float rden = 1.f / den;
  float acc[8];
#pragma unroll
  for (int j = 0; j < 8; ++j) acc[j] = 0.f;
  const unsigned short* whq = Whb + q * 8;
  for (int c0 = 0; c0 < deg; c0 += 16) {
    const int ce = min(16, deg - c0);
    float ar = 0.f;
    int sr = 0;
    if (c0 == 0) {
      sr = sreg;
      ar = __expf(vreg - m) * rden;
    } else {
      int i = c0 + q;
      if (i < deg) {
        int s = srcs[b0 + i];
        sr = s;
        float v = es[s] + edv;
        v = v > 0.f ? v : 0.2f * v;
        ar = __expf(v - m) * rden;
      }
    }
#pragma unroll 2
    for (int e = 0; e < ce; ++e) {
      int s = __shfl(sr, gbase + e);
      float a = __shfl(ar, gbase + e);
      bf16x8 v = *(const bf16x8*)&whq[(size_t)s * D];
#pragma unroll
      for (int j = 0; j < 8; ++j) {
        acc[j] += a * bf2f((unsigned short)v[j]);
      }
    }
  }
  float o[8];
#pragma unroll
  for (int j = 0; j < 8; ++j) o[j] = acc[j];
  if constexpr (EPI != 0) {
#pragma unroll
    for (int j = 0; j < 8; ++j) o[j] = o[j] > 0.f ? o[j] : expm1f(o[j]);
    uint4 pk;
    pk.x = (unsigned)f2b(o[0]) | ((unsigned)f2b(o[1]) << 16);
    pk.y = (unsigned)f2b(o[2]) | ((unsigned)f2b(o[3]) << 16);
    pk.z = (unsigned)f2b(o[4]) | ((unsigned)f2b(o[5]) << 16);
    pk.w = (unsigned)f2b(o[6]) | ((unsigned)f2b(o[7]) << 16);
    *(uint4*)&outb[(size_t)t * D + q * 8] = pk;
  }
  if constexpr (EPI != 2) {
    *(float4*)&outf[(size_t)t * D + q * 8] = make_float4(o[0], o[1], o[2], o[3]);
    *(float4*)&outf[(size_t)t * D + q * 8 + 4] = make_float4(o[4], o[5], o[6], o[7]);
  }
}

// ---------- fused GRU (16-row tiles): gi=xb@Wih^T; gh=hb@Whh^T; gates ----------
__global__ void __launch_bounds__(256) k_gru_mfma(const unsigned short* __restrict__ xb,
                                                  const unsigned short* __restrict__ hb,
                                                  const float* __restrict__ hf,
                                                  const unsigned short* __restrict__ Bih,
                                                  const unsigned short* __restrict__ Bhh,
                                                  const float* __restrict__ bih,
                                                  const float* __restrict__ bhh,
                                                  float* __restrict__ houtf,
                                                  unsigned short* __restrict__ houtb) {
  const int n0 = blockIdx.x * 16;
  const int w = threadIdx.x >> 6;
  const int lane = threadIdx.x & 63;
  const int r = lane & 15, g = lane >> 4;
  f32x4 ai[3][2], ah[3][2];
#pragma unroll
  for (int p = 0; p < 3; ++p)
#pragma unroll
    for (int t = 0; t < 2; ++t) {
      ai[p][t] = (f32x4)0.f;
      ah[p][t] = (f32x4)0.f;
    }
  const int koff = g << 3;
#pragma unroll
  for (int kb = 0; kb < 4; ++kb) {
    const size_t abase = (size_t)(n0 + r) * 128 + kb * 32 + koff;
    bf16x8 ax = *(const bf16x8*)&xb[abase];
    bf16x8 ahr = *(const bf16x8*)&hb[abase];
#pragma unroll
    for (int p = 0; p < 3; ++p) {
#pragma unroll
      for (int t = 0; t < 2; ++t) {
        const int ct = p * 8 + w * 2 + t;
        bf16x8 bi = *(const bf16x8*)&Bih[((size_t)(kb * 24 + ct) * 64 + lane) * 8];
        bf16x8 bh = *(const bf16x8*)&Bhh[((size_t)(kb * 24 + ct) * 64 + lane) * 8];
        ai[p][t] = __builtin_amdgcn_mfma_f32_16x16x32_bf16(ax, bi, ai[p][t], 0, 0, 0);
        ah[p][t] = __builtin_amdgcn_mfma_f32_16x16x32_bf16(ahr, bh, ah[p][t], 0, 0, 0);
      }
    }
  }
#pragma unroll
  for (int t = 0; t < 2; ++t) {
    const int j = (w * 2 + t) * 16 + r;
    const float bir = bih[j], biz = bih[128 + j], bin = bih[256 + j];
    const float bhr = bhh[j], bhz = bhh[128 + j], bhn = bhh[256 + j];
#pragma unroll
    for (int i = 0; i < 4; ++i) {
      const int row = n0 + g * 4 + i;
      float rr = sigmoidf_(ai[0][t][i] + bir + ah[0][t][i] + bhr);
      float z = sigmoidf_(ai[1][t][i] + biz + ah[1][t][i] + bhz);
      float nn = tanhf(ai[2][t][i] + bin + rr * (ah[2][t][i] + bhn));
      float hp = hf[(size_t)row * 128 + j];
      float o = (1.f - z) * nn + z * hp;
      houtf[(size_t)row * 128 + j] = o;
      houtb[(size_t)row * 128 + j] = f2b(o);
    }
  }
}

// ---------- final: out[n] = sigmoid(dot(h[n,:], W5) + b5) ----------
__global__ void __launch_bounds__(256) k_final(const float* __restrict__ h, const float* __restrict__ W5,
                                               const float* __restrict__ b5, float* __restrict__ out, int N) {
  int w = blockIdx.x * 4 + (threadIdx.x >> 6);
  int lane = threadIdx.x & 63;
  if (w >= N) return;
  float x = h[(size_t)w * D + lane] * W5[lane] + h[(size_t)w * D + lane + 64] * W5[lane + 64];
#pragma unroll
  for (int off = 32; off; off >>= 1) x += __shfl_down(x, off);
  if (lane == 0) out[w] = sigmoidf_(x + b5[0]);
}

extern "C" void kernel_launch(void* const* d_in, const int* in_sizes, int n_in,
                              void* d_out, int out_size, void* d_ws, size_t ws_size,
                              hipStream_t stream) {
  const float* h0 = (const float*)d_in[0];
  const int* ei = (const int*)d_in[1];
  const float* W1 = (const float*)d_in[2];
  const float* as1 = (const float*)d_in[3];
  const float* ad1 = (const float*)d_in[4];
  const float* W2 = (const float*)d_in[5];
  const float* as2 = (const float*)d_in[6];
  const float* ad2 = (const float*)d_in[7];
  const float* W3 = (const float*)d_in[8];
  const float* as3 = (const float*)d_in[9];
  const float* ad3 = (const float*)d_in[10];
  const float* W4 = (const float*)d_in[11];
  const float* as4 = (const float*)d_in[12];
  const float* ad4 = (const float*)d_in[13];
  const float* Wih = (const float*)d_in[14];
  const float* Whh = (const float*)d_in[15];
  const float* bih = (const float*)d_in[16];
  const float* bhh = (const float*)d_in[17];
  const float* W5 = (const float*)d_in[18];
  const float* b5 = (const float*)d_in[19];

  const int N = in_sizes[0] / D;  // 20000
  const int E = in_sizes[1] / 2;  // 320000
  const int* src = ei;
  const int* dst = ei + E;

  // ---- workspace layout ----
  float* ws = (float*)d_ws;
  unsigned short* Whb = (unsigned short*)ws;          // N*512 us
  float* hA = ws + (size_t)N * 256;                   // N*128 f32
  float* hB = hA + (size_t)N * 128;                   // N*128 f32
  unsigned short* xb = (unsigned short*)(hB + (size_t)N * 128);  // N*128 us
  float* es = (float*)(xb + (size_t)N * 128);         // N*4
  float* ed = es + (size_t)N * 4;                     // N*4
  unsigned short* h0b = (unsigned short*)(ed + (size_t)N * 4);   // N*128 us
  unsigned short* hAb = h0b + (size_t)N * 128;        // N*128 us
  unsigned short* hBb = hAb + (size_t)N * 128;        // N*128 us
  unsigned short* B1 = hBb + (size_t)N * 128;         // 65536 us
  unsigned short* B2 = B1 + 65536;                    // 65536 us
  unsigned short* B3 = B2 + 65536;                    // 65536 us
  unsigned short* B4 = B3 + 65536;                    // 16384 us
  unsigned short* Bih = B4 + 16384;                   // 49152 us
  unsigned short* Bhh = Bih + 49152;                  // 49152 us
  int* deg = (int*)(Bhh + 49152);                     // N
  int* rowptr = deg + N;                              // N+1
  int* fill = rowptr + N + 1;                         // N
  int* srcs = fill + N;                               // E

  // ---- one-time prep ----
  k_f2b<<<(N * 128 + 255) / 256, 256, 0, stream>>>(h0, h0b, N * 128);
  k_pack_all<<<1216, 256, 0, stream>>>(W1, W2, W3, W4, Wih, Whh, B1, B2, B3, B4, Bih, Bhh);
  hipMemsetAsync(deg, 0, (size_t)N * 4, stream);
  k_hist<<<(E + 255) / 256, 256, 0, stream>>>(dst, deg, E);
  k_scan<<<1, 1024, 0, stream>>>(deg, rowptr, fill, N);
  k_scatter<<<(E + 255) / 256, 256, 0, stream>>>(src, dst, fill, srcs, E);

  const int gW = N / 16;         // 1250
  const int gE4 = (N + 3) / 4;   // 5000
  const int gE1 = (N + 15) / 16; // 1250
  // ---- layer 1: H=4, no GRU; edge emits elu as f32 (hA) + bf16 (hAb) ----
  k_wh_mfma<512, true><<<gW, 256, 0, stream>>>(h0b, B1, Whb, as1, ad1, es, ed);
  k_edge_fused4<1><<<gE4, 256, 0, stream>>>(rowptr, srcs, es, ed, Whb, hA, hAb, N);
  // ---- layer 2: H=4, GRU; edge emits xb bf16 only ----
  k_wh_mfma<512, true><<<gW, 256, 0, stream>>>(hAb, B2, Whb, as2, ad2, es, ed);
  k_edge_fused4<2><<<gE4, 256, 0, stream>>>(rowptr, srcs, es, ed, Whb, nullptr, xb, N);
  k_gru_mfma<<<gW, 256, 0, stream>>>(xb, hAb, hA, Bih, Bhh, bih, bhh, hB, hBb);
  // ---- layer 3: H=4, GRU ----
  k_wh_mfma<512, true><<<gW, 256, 0, stream>>>(hBb, B3, Whb, as3, ad3, es, ed);
  k_edge_fused4<2><<<gE4, 256, 0, stream>>>(rowptr, srcs, es, ed, Whb, nullptr, xb, N);
  k_gru_mfma<<<gW, 256, 0, stream>>>(xb, hBb, hB, Bih, Bhh, bih, bhh, hA, hAb);
  // ---- layer 4: H=1, GRU ----
  k_wh_mfma<128, false><<<gW, 256, 0, stream>>>(hAb, B4, Whb, nullptr, nullptr, nullptr, nullptr);
  k_es_ed1<<<(N + 3) / 4, 256, 0, stream>>>(Whb, as4, ad4, es, ed, N);
  k_edge_fused1<2><<<gE1, 256, 0, stream>>>(rowptr, srcs, es, ed, Whb, nullptr, xb, N);
  k_gru_mfma<<<gW, 256, 0, stream>>>(xb, hAb, hA, Bih, Bhh, bih, bhh, hB, hBb);

  // ---- output head ----
  k_final<<<(N + 3) / 4, 256, 0, stream>>>(hB, W5, b5, (float*)d_out, N);
}